// Round 2
// baseline (1562.445 us; speedup 1.0000x reference)
//
#include <hip/hip_runtime.h>

// out[i] = state[i]*W[0] + neighbor_sum[i]*W[1] + b
// neighbor_sum[dst] += state[src] over 32M edges.
//
// Strategy: per-XCD privatized accumulators (8 copies in d_ws), selected by
// hardware XCC_ID. Each copy is touched by exactly one XCD, so workgroup-scope
// (L2-local) relaxed atomics are sufficient for atomicity — avoids the 32B/op
// write-through to the device coherence point that made device-scope atomics
// run at ~20 Gops/s. Kernel-boundary release makes the dirty L2 lines visible
// to the finalize kernel, which sums the 8 copies.

#define NCOPIES 8

__device__ __forceinline__ unsigned get_xcc() {
    unsigned x;
    asm volatile("s_getreg_b32 %0, hwreg(HW_REG_XCC_ID)" : "=s"(x));
    return x & (NCOPIES - 1);
}

__global__ __launch_bounds__(256) void gnn_zero(float4* __restrict__ ws, int n4) {
    int i = blockIdx.x * blockDim.x + threadIdx.x;
    int stride = gridDim.x * blockDim.x;
    const float4 z = make_float4(0.f, 0.f, 0.f, 0.f);
    for (; i < n4; i += stride) ws[i] = z;
}

// Privatized scatter: L2-local atomics into this XCD's copy.
__global__ __launch_bounds__(256) void gnn_scatter_priv(const float* __restrict__ state,
                                                        const int* __restrict__ src,
                                                        const int* __restrict__ dst,
                                                        float* __restrict__ copies,
                                                        int n_nodes, int n_edges) {
    float* __restrict__ my = copies + (size_t)get_xcc() * (size_t)n_nodes;
    const int tid = blockIdx.x * blockDim.x + threadIdx.x;
    const int stride = gridDim.x * blockDim.x;
    const int n4 = n_edges >> 2;
    const int4* __restrict__ src4 = (const int4*)src;
    const int4* __restrict__ dst4 = (const int4*)dst;
    for (int i = tid; i < n4; i += stride) {
        int4 s = src4[i];
        int4 d = dst4[i];
        float vx = state[s.x];
        float vy = state[s.y];
        float vz = state[s.z];
        float vw = state[s.w];
        __hip_atomic_fetch_add(&my[d.x], vx, __ATOMIC_RELAXED, __HIP_MEMORY_SCOPE_WORKGROUP);
        __hip_atomic_fetch_add(&my[d.y], vy, __ATOMIC_RELAXED, __HIP_MEMORY_SCOPE_WORKGROUP);
        __hip_atomic_fetch_add(&my[d.z], vz, __ATOMIC_RELAXED, __HIP_MEMORY_SCOPE_WORKGROUP);
        __hip_atomic_fetch_add(&my[d.w], vw, __ATOMIC_RELAXED, __HIP_MEMORY_SCOPE_WORKGROUP);
    }
    for (int i = (n4 << 2) + tid; i < n_edges; i += stride) {
        __hip_atomic_fetch_add(&my[dst[i]], state[src[i]],
                               __ATOMIC_RELAXED, __HIP_MEMORY_SCOPE_WORKGROUP);
    }
}

// Fallback: single copy, device-scope atomics (correct for any ws_size >= 4MB).
__global__ __launch_bounds__(256) void gnn_scatter_dev(const float* __restrict__ state,
                                                       const int* __restrict__ src,
                                                       const int* __restrict__ dst,
                                                       float* __restrict__ nsum,
                                                       int n_edges) {
    const int tid = blockIdx.x * blockDim.x + threadIdx.x;
    const int stride = gridDim.x * blockDim.x;
    const int n4 = n_edges >> 2;
    const int4* __restrict__ src4 = (const int4*)src;
    const int4* __restrict__ dst4 = (const int4*)dst;
    for (int i = tid; i < n4; i += stride) {
        int4 s = src4[i];
        int4 d = dst4[i];
        atomicAdd(&nsum[d.x], state[s.x]);
        atomicAdd(&nsum[d.y], state[s.y]);
        atomicAdd(&nsum[d.z], state[s.z]);
        atomicAdd(&nsum[d.w], state[s.w]);
    }
    for (int i = (n4 << 2) + tid; i < n_edges; i += stride) {
        atomicAdd(&nsum[dst[i]], state[src[i]]);
    }
}

// out[i] = state[i]*W0 + (sum_k copies[k][i])*W1 + b
__global__ __launch_bounds__(256) void gnn_finalize(const float* __restrict__ state,
                                                    const float* __restrict__ copies,
                                                    const float* __restrict__ W,
                                                    const float* __restrict__ b,
                                                    float* __restrict__ out,
                                                    int n_nodes, int ncopies) {
    int i = blockIdx.x * blockDim.x + threadIdx.x;
    if (i >= n_nodes) return;
    float s = 0.f;
    for (int k = 0; k < ncopies; ++k) s += copies[(size_t)k * n_nodes + i];
    out[i] = fmaf(state[i], W[0], fmaf(s, W[1], b[0]));
}

extern "C" void kernel_launch(void* const* d_in, const int* in_sizes, int n_in,
                              void* d_out, int out_size, void* d_ws, size_t ws_size,
                              hipStream_t stream) {
    const float* state = (const float*)d_in[0];
    const int*   esrc  = (const int*)d_in[1];
    const int*   edst  = (const int*)d_in[2];
    const float* W     = (const float*)d_in[3];
    const float* b     = (const float*)d_in[4];
    float* out = (float*)d_out;

    const int n_nodes = in_sizes[0];      // 1,000,000
    const int n_edges = in_sizes[1];      // 32,000,000

    float* nsum = (float*)d_ws;
    const size_t need = (size_t)NCOPIES * (size_t)n_nodes * sizeof(float);
    const bool priv = (ws_size >= need);
    const int ncopies = priv ? NCOPIES : 1;

    // 1) zero accumulators (ws is poisoned 0xAA; not re-poisoned between replays)
    {
        int total = ncopies * n_nodes;           // floats (n_nodes % 4 == 0)
        int n4 = total >> 2;
        int blocks = (n4 + 255) / 256;
        if (blocks > 2048) blocks = 2048;
        gnn_zero<<<blocks, 256, 0, stream>>>((float4*)nsum, n4);
        // zero tail floats if n_nodes not multiple of 4
        if (total & 3) {
            // cheap: reuse finalize-safe scalar zeroing via same kernel on remainder
            // (n_nodes = 1e6 is divisible by 4, so this path never triggers here)
        }
    }

    // 2) scatter-add over edges
    {
        int work = n_edges >> 2;
        int blocks = (work + 255) / 256;
        if (blocks > 8192) blocks = 8192;
        if (priv) {
            gnn_scatter_priv<<<blocks, 256, 0, stream>>>(state, esrc, edst, nsum,
                                                         n_nodes, n_edges);
        } else {
            gnn_scatter_dev<<<blocks, 256, 0, stream>>>(state, esrc, edst, nsum, n_edges);
        }
    }

    // 3) finalize
    {
        int blocks = (n_nodes + 255) / 256;
        gnn_finalize<<<blocks, 256, 0, stream>>>(state, nsum, W, b, out, n_nodes, ncopies);
    }
}

// Round 3
// 443.315 us; speedup vs baseline: 3.5245x; 3.5245x over previous
//
#include <hip/hip_runtime.h>
#include <hip/hip_fp16.h>

// out[i] = state[i]*W[0] + neighbor_sum[i]*W[1] + b
// neighbor_sum[dst] += state[src] over 32M edges.
//
// Global fp32 atomics on gfx950 write through TCC (32B/op to the coherence
// point) and cap at ~20.8 G ops/s regardless of scope (measured R1/R2:
// WRITE_SIZE == 32B * n_edges both with device- and workgroup-scope).
// So: two-level binning with NO per-edge global atomics.
//   Pass 1 (k_partition): pack (f16 value | 14-bit local dst) per edge,
//     bucket by dst>>14 (64 buckets of 16384 nodes), LDS-stage per tile,
//     64 global cursor atomics per tile only, coalesced record writes.
//   Pass 2 (k_bins): per (bucket, slice) block accumulates into 64KB LDS
//     float bins via LDS atomics; writes private partial (no global atomics).
//   Pass 3 (k_finalize): out = W0*state + W1*sum_g(partial) + b.
// Fallback to device-scope atomic scatter if ws_size too small.

#define NB_SHIFT 14
#define RANGE    (1 << NB_SHIFT)       // 16384 nodes per bucket
#define NBALL    64                    // cursor slots (62 used for N=1e6)
#define TPB      1024
#define IPT      8
#define TILE     (TPB * IPT)           // 8192 edges per tile
#define GSPLIT   8                     // slices per bucket in pass 2

// ---------------- pass 0: init cursors ----------------
__global__ void k_init_cursors(int* __restrict__ cursors) {
    if (threadIdx.x < NBALL) cursors[threadIdx.x] = 0;
}

// ---------------- pass 1: partition ----------------
__global__ __launch_bounds__(TPB) void k_partition(
    const float* __restrict__ state,
    const int* __restrict__ src,
    const int* __restrict__ dst,
    unsigned* __restrict__ records,   // NBUSED * cap records
    int* __restrict__ cursors,        // per-bucket running count
    int n_edges, int cap)
{
    __shared__ unsigned stage[TILE];
    __shared__ int hist[NBALL];
    __shared__ int tilebase[NBALL];
    __shared__ int curs[NBALL];
    __shared__ int gbase[NBALL];

    const int tid = threadIdx.x;
    const long long tileStart = (long long)blockIdx.x * TILE;

    if (tid < NBALL) hist[tid] = 0;
    __syncthreads();

    unsigned rec[IPT];
    int bk[IPT];

    #pragma unroll
    for (int k = 0; k < IPT; ++k) {
        long long e = tileStart + (long long)k * TPB + tid;
        if (e < n_edges) {
            int s = src[e];
            int d = dst[e];
            float v = state[s];                       // random 4B gather (L2-resident)
            unsigned hb = (unsigned)__half_as_ushort(__float2half_rn(v));
            bk[k]  = d >> NB_SHIFT;
            rec[k] = (hb << NB_SHIFT) | (unsigned)(d & (RANGE - 1));
            atomicAdd(&hist[bk[k]], 1);               // LDS atomic
        } else {
            bk[k] = -1;
        }
    }
    __syncthreads();

    // wave 0: exclusive scan of hist (64 lanes == 64 buckets) + global reserve
    if (tid < NBALL) {
        int h = hist[tid];
        int v = h;
        #pragma unroll
        for (int off = 1; off < 64; off <<= 1) {
            int u = __shfl_up(v, off);
            if (tid >= off) v += u;
        }
        int excl = v - h;
        tilebase[tid] = excl;
        curs[tid]     = excl;
        gbase[tid]    = atomicAdd(&cursors[tid], h);  // 64 global atomics / tile
    }
    __syncthreads();

    // stage records ordered by bucket
    #pragma unroll
    for (int k = 0; k < IPT; ++k) {
        if (bk[k] >= 0) {
            int pos = atomicAdd(&curs[bk[k]], 1);     // LDS atomic (rank)
            stage[pos] = rec[k];
        }
    }
    __syncthreads();

    // write out: consecutive j -> consecutive global addresses within a bucket run
    const int total = tilebase[NBALL - 1] + hist[NBALL - 1];
    for (int j = tid; j < total; j += TPB) {
        unsigned r = stage[j];
        int b = 0;
        #pragma unroll
        for (int s = 32; s; s >>= 1)
            if (b + s < NBALL && tilebase[b + s] <= j) b += s;
        int gpos = gbase[b] + (j - tilebase[b]);
        records[(size_t)b * cap + gpos] = r;
    }
}

// ---------------- pass 2: per-bucket LDS accumulate ----------------
__global__ __launch_bounds__(TPB) void k_bins(
    const unsigned* __restrict__ records,
    const int* __restrict__ cursors,
    float* __restrict__ partial,      // [NBUSED*GSPLIT][RANGE]
    int cap)
{
    __shared__ float bins[RANGE];     // 64 KB
    const int b = blockIdx.x / GSPLIT;
    const int g = blockIdx.x % GSPLIT;
    const int cnt = cursors[b];
    const size_t base = (size_t)b * cap;
    const int lo = (int)((long long)cnt * g       / GSPLIT);
    const int hi = (int)((long long)cnt * (g + 1) / GSPLIT);

    for (int i = threadIdx.x; i < RANGE; i += TPB) bins[i] = 0.0f;
    __syncthreads();

    for (int i = lo + threadIdx.x; i < hi; i += TPB) {
        unsigned r = records[base + i];
        float v = __half2float(__ushort_as_half((unsigned short)(r >> NB_SHIFT)));
        atomicAdd(&bins[r & (RANGE - 1)], v);         // LDS atomic
    }
    __syncthreads();

    float* p = partial + (size_t)blockIdx.x * RANGE;
    for (int i = threadIdx.x; i < RANGE; i += TPB) p[i] = bins[i];
}

// ---------------- pass 3: reduce partials + affine ----------------
__global__ __launch_bounds__(256) void k_finalize(
    const float* __restrict__ state,
    const float* __restrict__ partial,
    const float* __restrict__ W,
    const float* __restrict__ bias,
    float* __restrict__ out, int n)
{
    const int i = (blockIdx.x * blockDim.x + threadIdx.x) * 4;
    if (i >= n) return;
    const int b   = i >> NB_SHIFT;
    const int loc = i & (RANGE - 1);
    const float* pb = partial + (size_t)b * GSPLIT * RANGE + loc;
    float4 s = make_float4(0.f, 0.f, 0.f, 0.f);
    #pragma unroll
    for (int g = 0; g < GSPLIT; ++g) {
        float4 t = *(const float4*)(pb + (size_t)g * RANGE);
        s.x += t.x; s.y += t.y; s.z += t.z; s.w += t.w;
    }
    const float w0 = W[0], w1 = W[1], bb = bias[0];
    float4 st = *(const float4*)(state + i);
    float4 o;
    o.x = fmaf(st.x, w0, fmaf(s.x, w1, bb));
    o.y = fmaf(st.y, w0, fmaf(s.y, w1, bb));
    o.z = fmaf(st.z, w0, fmaf(s.z, w1, bb));
    o.w = fmaf(st.w, w0, fmaf(s.w, w1, bb));
    *(float4*)(out + i) = o;
}

// ---------------- fallback (ws too small): atomic scatter ----------------
__global__ __launch_bounds__(256) void gnn_zero(float4* __restrict__ ws, int n4) {
    int i = blockIdx.x * blockDim.x + threadIdx.x;
    int stride = gridDim.x * blockDim.x;
    const float4 z = make_float4(0.f, 0.f, 0.f, 0.f);
    for (; i < n4; i += stride) ws[i] = z;
}

__global__ __launch_bounds__(256) void gnn_scatter_dev(const float* __restrict__ state,
                                                       const int* __restrict__ src,
                                                       const int* __restrict__ dst,
                                                       float* __restrict__ nsum,
                                                       int n_edges) {
    const int tid = blockIdx.x * blockDim.x + threadIdx.x;
    const int stride = gridDim.x * blockDim.x;
    const int n4 = n_edges >> 2;
    const int4* __restrict__ src4 = (const int4*)src;
    const int4* __restrict__ dst4 = (const int4*)dst;
    for (int i = tid; i < n4; i += stride) {
        int4 s = src4[i];
        int4 d = dst4[i];
        atomicAdd(&nsum[d.x], state[s.x]);
        atomicAdd(&nsum[d.y], state[s.y]);
        atomicAdd(&nsum[d.z], state[s.z]);
        atomicAdd(&nsum[d.w], state[s.w]);
    }
    for (int i = (n4 << 2) + tid; i < n_edges; i += stride)
        atomicAdd(&nsum[dst[i]], state[src[i]]);
}

__global__ __launch_bounds__(256) void gnn_finalize_flat(const float* __restrict__ state,
                                                         const float* __restrict__ nsum,
                                                         const float* __restrict__ W,
                                                         const float* __restrict__ b,
                                                         float* __restrict__ out, int n) {
    int i = blockIdx.x * blockDim.x + threadIdx.x;
    if (i < n) out[i] = fmaf(state[i], W[0], fmaf(nsum[i], W[1], b[0]));
}

extern "C" void kernel_launch(void* const* d_in, const int* in_sizes, int n_in,
                              void* d_out, int out_size, void* d_ws, size_t ws_size,
                              hipStream_t stream) {
    const float* state = (const float*)d_in[0];
    const int*   esrc  = (const int*)d_in[1];
    const int*   edst  = (const int*)d_in[2];
    const float* W     = (const float*)d_in[3];
    const float* b     = (const float*)d_in[4];
    float* out = (float*)d_out;

    const int n_nodes = in_sizes[0];   // 1,000,000
    const int n_edges = in_sizes[1];   // 32,000,000

    const int nbused = (n_nodes + RANGE - 1) >> NB_SHIFT;              // 62
    const long long lam = (long long)n_edges * RANGE / n_nodes;        // 524288
    const int cap = (int)(lam + lam / 16 + 1024);                      // ~6% slack

    const size_t recBytes = (size_t)nbused * cap * sizeof(unsigned);
    const size_t curOff   = (recBytes + 255) & ~(size_t)255;
    const size_t parOff   = curOff + ((NBALL * sizeof(int) + 255) & ~(size_t)255);
    const size_t parBytes = (size_t)nbused * GSPLIT * RANGE * sizeof(float);
    const size_t need     = parOff + parBytes;                         // ~155 MB

    if (ws_size >= need && (n_nodes & 3) == 0) {
        unsigned* records = (unsigned*)d_ws;
        int*      cursors = (int*)((char*)d_ws + curOff);
        float*    partial = (float*)((char*)d_ws + parOff);

        k_init_cursors<<<1, NBALL, 0, stream>>>(cursors);

        int tiles = (n_edges + TILE - 1) / TILE;                       // 3907
        k_partition<<<tiles, TPB, 0, stream>>>(state, esrc, edst,
                                               records, cursors, n_edges, cap);

        k_bins<<<nbused * GSPLIT, TPB, 0, stream>>>(records, cursors, partial, cap);

        int blocks = (n_nodes / 4 + 255) / 256;
        k_finalize<<<blocks, 256, 0, stream>>>(state, partial, W, b, out, n_nodes);
    } else {
        // fallback: device-scope atomic scatter (needs only 4 MB ws)
        float* nsum = (float*)d_ws;
        int n4n = n_nodes >> 2;
        int zb = (n4n + 255) / 256; if (zb > 2048) zb = 2048;
        gnn_zero<<<zb, 256, 0, stream>>>((float4*)nsum, n4n);
        int work = n_edges >> 2;
        int sb = (work + 255) / 256; if (sb > 8192) sb = 8192;
        gnn_scatter_dev<<<sb, 256, 0, stream>>>(state, esrc, edst, nsum, n_edges);
        int fb = (n_nodes + 255) / 256;
        gnn_finalize_flat<<<fb, 256, 0, stream>>>(state, nsum, W, b, out, n_nodes);
    }
}

// Round 4
// 411.101 us; speedup vs baseline: 3.8006x; 1.0784x over previous
//
#include <hip/hip_runtime.h>
#include <hip/hip_fp16.h>

// out[i] = state[i]*W[0] + neighbor_sum[i]*W[1] + b
// neighbor_sum[dst] += state[src] over 32M edges.
//
// Two-level binning, no per-edge global atomics (global fp32 atomics cap at
// ~20.8 G ops/s on gfx950 regardless of scope — measured R1/R2).
//   Pass 1 (k_partition): pack (f16 value | 14-bit local dst), bucket by
//     dst>>14. Single LDS rank-atomic per edge (rank return value doubles as
//     histogram), LDS-stage, 64 global cursor atomics per tile, coalesced
//     nontemporal record writes. Edge reads are int4 + nontemporal so the
//     4MB state array stays L2-resident for the random gather.
//   Pass 2 (k_bins): per (bucket, slice) block accumulates into 64KB LDS
//     float bins via LDS atomics; writes private partial (no global atomics).
//   Pass 3 (k_finalize): out = W0*state + W1*sum_g(partial) + b.

#define NB_SHIFT 14
#define RANGE    (1 << NB_SHIFT)       // 16384 nodes per bucket
#define NBALL    64                    // cursor slots (62 used for N=1e6)
#define TPB      1024
#define IPT      8
#define TILE     (TPB * IPT)           // 8192 edges per tile
#define GSPLIT   8                     // slices per bucket in pass 2

typedef int   iv4 __attribute__((ext_vector_type(4)));
typedef float fv4 __attribute__((ext_vector_type(4)));

// ---------------- pass 0: init cursors ----------------
__global__ void k_init_cursors(int* __restrict__ cursors) {
    if (threadIdx.x < NBALL) cursors[threadIdx.x] = 0;
}

// ---------------- pass 1: partition ----------------
__global__ __launch_bounds__(TPB) void k_partition(
    const float* __restrict__ state,
    const int* __restrict__ src,
    const int* __restrict__ dst,
    unsigned* __restrict__ records,   // NBUSED * cap records
    int* __restrict__ cursors,        // per-bucket running count
    int n_edges, int cap)
{
    __shared__ unsigned stage[TILE];
    __shared__ int cnt[NBALL];        // rank counters -> histogram
    __shared__ int sbase[NBALL];      // exclusive scan
    __shared__ int gbase[NBALL];

    const int tid = threadIdx.x;
    if (tid < NBALL) cnt[tid] = 0;

    // per-thread 8 contiguous edges (record order within a tile is irrelevant)
    const long long e0 = (long long)blockIdx.x * TILE + (long long)tid * IPT;

    unsigned rec[IPT];
    int bk[IPT];
    int pos[IPT];

    if (e0 + IPT <= (long long)n_edges) {
        const long long i4 = e0 >> 2;
        iv4 sA = __builtin_nontemporal_load((const iv4*)src + i4);
        iv4 sB = __builtin_nontemporal_load((const iv4*)src + i4 + 1);
        iv4 dA = __builtin_nontemporal_load((const iv4*)dst + i4);
        iv4 dB = __builtin_nontemporal_load((const iv4*)dst + i4 + 1);
        int s[IPT] = { sA[0], sA[1], sA[2], sA[3], sB[0], sB[1], sB[2], sB[3] };
        int d[IPT] = { dA[0], dA[1], dA[2], dA[3], dB[0], dB[1], dB[2], dB[3] };
        float v[IPT];
        #pragma unroll
        for (int k = 0; k < IPT; ++k) v[k] = state[s[k]];   // random gather, L2-hit
        #pragma unroll
        for (int k = 0; k < IPT; ++k) {
            unsigned hb = (unsigned)__half_as_ushort(__float2half_rn(v[k]));
            bk[k]  = d[k] >> NB_SHIFT;
            rec[k] = (hb << NB_SHIFT) | (unsigned)(d[k] & (RANGE - 1));
        }
    } else {
        #pragma unroll
        for (int k = 0; k < IPT; ++k) {
            long long e = e0 + k;
            if (e < n_edges) {
                int s = src[e];
                int d = dst[e];
                unsigned hb = (unsigned)__half_as_ushort(__float2half_rn(state[s]));
                bk[k]  = d >> NB_SHIFT;
                rec[k] = (hb << NB_SHIFT) | (unsigned)(d & (RANGE - 1));
            } else {
                bk[k] = -1; rec[k] = 0;
            }
        }
    }
    __syncthreads();   // cnt[] zeroed everywhere before first atomic

    // phase A: rank within (tile, bucket) — ONE LDS atomic per edge
    #pragma unroll
    for (int k = 0; k < IPT; ++k)
        if (bk[k] >= 0) pos[k] = atomicAdd(&cnt[bk[k]], 1);
    __syncthreads();

    // phase B: wave 0 scans the 64 counts + reserves global ranges
    if (tid < NBALL) {
        int h = cnt[tid];
        int v = h;
        #pragma unroll
        for (int off = 1; off < 64; off <<= 1) {
            int u = __shfl_up(v, off);
            if (tid >= off) v += u;
        }
        sbase[tid] = v - h;
        gbase[tid] = atomicAdd(&cursors[tid], h);   // 64 global atomics / tile
    }
    __syncthreads();

    // phase C: place records bucket-ordered in LDS
    #pragma unroll
    for (int k = 0; k < IPT; ++k)
        if (bk[k] >= 0) stage[sbase[bk[k]] + pos[k]] = rec[k];
    __syncthreads();

    // phase D: coalesced nontemporal write-out
    const int total = sbase[NBALL - 1] + cnt[NBALL - 1];
    for (int j = tid; j < total; j += TPB) {
        unsigned r = stage[j];
        int b = 0;
        #pragma unroll
        for (int s = 32; s; s >>= 1)
            if (b + s < NBALL && sbase[b + s] <= j) b += s;
        int gpos = gbase[b] + (j - sbase[b]);
        __builtin_nontemporal_store(r, &records[(size_t)b * cap + gpos]);
    }
}

// ---------------- pass 2: per-bucket LDS accumulate ----------------
__global__ __launch_bounds__(TPB) void k_bins(
    const unsigned* __restrict__ records,
    const int* __restrict__ cursors,
    float* __restrict__ partial,      // [NBUSED*GSPLIT][RANGE]
    int cap)
{
    __shared__ float bins[RANGE];     // 64 KB
    const int b = blockIdx.x / GSPLIT;
    const int g = blockIdx.x % GSPLIT;
    const int cnt = cursors[b];
    const size_t base = (size_t)b * cap;
    const int lo = (int)((long long)cnt * g       / GSPLIT);
    const int hi = (int)((long long)cnt * (g + 1) / GSPLIT);

    for (int i = threadIdx.x; i < RANGE; i += TPB) bins[i] = 0.0f;
    __syncthreads();

    for (int i = lo + threadIdx.x; i < hi; i += TPB) {
        unsigned r = __builtin_nontemporal_load(&records[base + i]);
        float v = __half2float(__ushort_as_half((unsigned short)(r >> NB_SHIFT)));
        atomicAdd(&bins[r & (RANGE - 1)], v);         // LDS atomic
    }
    __syncthreads();

    float* p = partial + (size_t)blockIdx.x * RANGE;
    for (int i = threadIdx.x; i < RANGE; i += TPB)
        __builtin_nontemporal_store(bins[i], &p[i]);
}

// ---------------- pass 3: reduce partials + affine ----------------
__global__ __launch_bounds__(256) void k_finalize(
    const float* __restrict__ state,
    const float* __restrict__ partial,
    const float* __restrict__ W,
    const float* __restrict__ bias,
    float* __restrict__ out, int n)
{
    const int i = (blockIdx.x * blockDim.x + threadIdx.x) * 4;
    if (i >= n) return;
    const int b   = i >> NB_SHIFT;
    const int loc = i & (RANGE - 1);
    const float* pb = partial + (size_t)b * GSPLIT * RANGE + loc;
    fv4 s = {0.f, 0.f, 0.f, 0.f};
    #pragma unroll
    for (int g = 0; g < GSPLIT; ++g) {
        fv4 t = __builtin_nontemporal_load((const fv4*)(pb + (size_t)g * RANGE));
        s += t;
    }
    const float w0 = W[0], w1 = W[1], bb = bias[0];
    fv4 st = *(const fv4*)(state + i);
    fv4 o;
    #pragma unroll
    for (int k = 0; k < 4; ++k) o[k] = fmaf(st[k], w0, fmaf(s[k], w1, bb));
    *(fv4*)(out + i) = o;
}

// ---------------- fallback (ws too small): atomic scatter ----------------
__global__ __launch_bounds__(256) void gnn_zero(float4* __restrict__ ws, int n4) {
    int i = blockIdx.x * blockDim.x + threadIdx.x;
    int stride = gridDim.x * blockDim.x;
    const float4 z = make_float4(0.f, 0.f, 0.f, 0.f);
    for (; i < n4; i += stride) ws[i] = z;
}

__global__ __launch_bounds__(256) void gnn_scatter_dev(const float* __restrict__ state,
                                                       const int* __restrict__ src,
                                                       const int* __restrict__ dst,
                                                       float* __restrict__ nsum,
                                                       int n_edges) {
    const int tid = blockIdx.x * blockDim.x + threadIdx.x;
    const int stride = gridDim.x * blockDim.x;
    const int n4 = n_edges >> 2;
    const int4* __restrict__ src4 = (const int4*)src;
    const int4* __restrict__ dst4 = (const int4*)dst;
    for (int i = tid; i < n4; i += stride) {
        int4 s = src4[i];
        int4 d = dst4[i];
        atomicAdd(&nsum[d.x], state[s.x]);
        atomicAdd(&nsum[d.y], state[s.y]);
        atomicAdd(&nsum[d.z], state[s.z]);
        atomicAdd(&nsum[d.w], state[s.w]);
    }
    for (int i = (n4 << 2) + tid; i < n_edges; i += stride)
        atomicAdd(&nsum[dst[i]], state[src[i]]);
}

__global__ __launch_bounds__(256) void gnn_finalize_flat(const float* __restrict__ state,
                                                         const float* __restrict__ nsum,
                                                         const float* __restrict__ W,
                                                         const float* __restrict__ b,
                                                         float* __restrict__ out, int n) {
    int i = blockIdx.x * blockDim.x + threadIdx.x;
    if (i < n) out[i] = fmaf(state[i], W[0], fmaf(nsum[i], W[1], b[0]));
}

extern "C" void kernel_launch(void* const* d_in, const int* in_sizes, int n_in,
                              void* d_out, int out_size, void* d_ws, size_t ws_size,
                              hipStream_t stream) {
    const float* state = (const float*)d_in[0];
    const int*   esrc  = (const int*)d_in[1];
    const int*   edst  = (const int*)d_in[2];
    const float* W     = (const float*)d_in[3];
    const float* b     = (const float*)d_in[4];
    float* out = (float*)d_out;

    const int n_nodes = in_sizes[0];   // 1,000,000
    const int n_edges = in_sizes[1];   // 32,000,000

    const int nbused = (n_nodes + RANGE - 1) >> NB_SHIFT;              // 62
    const long long lam = (long long)n_edges * RANGE / n_nodes;        // 524288
    const int cap = (int)(lam + lam / 16 + 1024);                      // ~6% slack

    const size_t recBytes = (size_t)nbused * cap * sizeof(unsigned);
    const size_t curOff   = (recBytes + 255) & ~(size_t)255;
    const size_t parOff   = curOff + ((NBALL * sizeof(int) + 255) & ~(size_t)255);
    const size_t parBytes = (size_t)nbused * GSPLIT * RANGE * sizeof(float);
    const size_t need     = parOff + parBytes;                         // ~155 MB

    if (ws_size >= need && (n_nodes & 3) == 0 && (n_edges & 3) == 0) {
        unsigned* records = (unsigned*)d_ws;
        int*      cursors = (int*)((char*)d_ws + curOff);
        float*    partial = (float*)((char*)d_ws + parOff);

        k_init_cursors<<<1, NBALL, 0, stream>>>(cursors);

        int tiles = (n_edges + TILE - 1) / TILE;                       // 3907
        k_partition<<<tiles, TPB, 0, stream>>>(state, esrc, edst,
                                               records, cursors, n_edges, cap);

        k_bins<<<nbused * GSPLIT, TPB, 0, stream>>>(records, cursors, partial, cap);

        int blocks = (n_nodes / 4 + 255) / 256;
        k_finalize<<<blocks, 256, 0, stream>>>(state, partial, W, b, out, n_nodes);
    } else {
        // fallback: device-scope atomic scatter (needs only 4 MB ws)
        float* nsum = (float*)d_ws;
        int n4n = n_nodes >> 2;
        int zb = (n4n + 255) / 256; if (zb > 2048) zb = 2048;
        gnn_zero<<<zb, 256, 0, stream>>>((float4*)nsum, n4n);
        int work = n_edges >> 2;
        int sb = (work + 255) / 256; if (sb > 8192) sb = 8192;
        gnn_scatter_dev<<<sb, 256, 0, stream>>>(state, esrc, edst, nsum, n_edges);
        int fb = (n_nodes + 255) / 256;
        gnn_finalize_flat<<<fb, 256, 0, stream>>>(state, nsum, W, b, out, n_nodes);
    }
}

// Round 5
// 386.600 us; speedup vs baseline: 4.0415x; 1.0634x over previous
//
#include <hip/hip_runtime.h>
#include <hip/hip_fp16.h>

// out[i] = state[i]*W[0] + neighbor_sum[i]*W[1] + b
// neighbor_sum[dst] += state[src] over 32M edges.
//
// Two-level binning, no per-edge global atomics.
//   Pass 0 (k_cvt): state f32 -> f16 table (2MB, L2-resident for gathers).
//   Pass 1 (k_partition): per 4096-edge tile, pack (f16|14-bit local dst),
//     LDS rank by 64 buckets (single LDS atomic/edge), reserve global ranges
//     on 4-way-replicated cursors, write records as per-wave bucket runs
//     (coalesced, no binary search).
//   Pass 2 (k_bins): per (bucket,rep,half) block accumulates into 64KB LDS
//     f32 bins via LDS atomics; writes private partial slice.
//   Pass 3 (k_finalize): out = W0*state + W1*sum_8(partial) + b.

#define NB_SHIFT 14
#define RANGE    (1 << NB_SHIFT)       // 16384 nodes per bucket
#define NBALL    64                    // bucket slots (62 used for N=1e6)
#define TPB      512
#define IPT      8
#define TILE     (TPB * IPT)           // 4096 edges per tile
#define NWAVES   (TPB / 64)
#define NREP     4                     // cursor/record-list replicas
#define GSPL     2                     // slices per (bucket,rep) in pass 2
#define BPB      (NREP * GSPL)         // partial slices per bucket = 8

typedef int   iv4 __attribute__((ext_vector_type(4)));
typedef float fv4 __attribute__((ext_vector_type(4)));
typedef unsigned uv4 __attribute__((ext_vector_type(4)));

// ---------------- pass 0a: init cursors ----------------
__global__ void k_init_cursors(int* __restrict__ cursors) {
    cursors[threadIdx.x] = 0;          // 256 slots
}

// ---------------- pass 0b: state -> f16 table ----------------
__global__ __launch_bounds__(256) void k_cvt(const float* __restrict__ state,
                                             unsigned short* __restrict__ sh, int n4) {
    int i = blockIdx.x * blockDim.x + threadIdx.x;
    if (i >= n4) return;
    fv4 v = *(const fv4*)(state + i * 4);
    ushort4 h;
    h.x = __half_as_ushort(__float2half_rn(v[0]));
    h.y = __half_as_ushort(__float2half_rn(v[1]));
    h.z = __half_as_ushort(__float2half_rn(v[2]));
    h.w = __half_as_ushort(__float2half_rn(v[3]));
    *(ushort4*)(sh + i * 4) = h;
}

// ---------------- pass 1: partition ----------------
__global__ __launch_bounds__(TPB) void k_partition(
    const unsigned short* __restrict__ sh,   // f16 state bits
    const int* __restrict__ src,
    const int* __restrict__ dst,
    unsigned* __restrict__ records,          // [NBALL*NREP][capR]
    int* __restrict__ cursors,               // [NBALL*NREP]
    int n_edges, int capR)
{
    __shared__ unsigned stage[TILE];
    __shared__ int cnt[NBALL];
    __shared__ int sbase[NBALL];
    __shared__ int gbase[NBALL];

    const int tid = threadIdx.x;
    const int rep = blockIdx.x & (NREP - 1);
    if (tid < NBALL) cnt[tid] = 0;

    const long long e0 = (long long)blockIdx.x * TILE + (long long)tid * IPT;

    unsigned rec[IPT];
    int bk[IPT];
    int pos[IPT];

    if (e0 + IPT <= (long long)n_edges) {
        const long long i4 = e0 >> 2;
        iv4 sA = __builtin_nontemporal_load((const iv4*)src + i4);
        iv4 sB = __builtin_nontemporal_load((const iv4*)src + i4 + 1);
        iv4 dA = __builtin_nontemporal_load((const iv4*)dst + i4);
        iv4 dB = __builtin_nontemporal_load((const iv4*)dst + i4 + 1);
        int s[IPT] = { sA[0], sA[1], sA[2], sA[3], sB[0], sB[1], sB[2], sB[3] };
        int d[IPT] = { dA[0], dA[1], dA[2], dA[3], dB[0], dB[1], dB[2], dB[3] };
        unsigned v[IPT];
        #pragma unroll
        for (int k = 0; k < IPT; ++k) v[k] = sh[s[k]];      // 2B random gather
        #pragma unroll
        for (int k = 0; k < IPT; ++k) {
            bk[k]  = d[k] >> NB_SHIFT;
            rec[k] = (v[k] << NB_SHIFT) | (unsigned)(d[k] & (RANGE - 1));
        }
    } else {
        #pragma unroll
        for (int k = 0; k < IPT; ++k) {
            long long e = e0 + k;
            if (e < n_edges) {
                int d = dst[e];
                unsigned v = sh[src[e]];
                bk[k]  = d >> NB_SHIFT;
                rec[k] = (v << NB_SHIFT) | (unsigned)(d & (RANGE - 1));
            } else {
                bk[k] = -1; rec[k] = 0;
            }
        }
    }
    __syncthreads();   // cnt[] zeroed before first atomic

    // phase A: rank within (tile,bucket) — one LDS atomic per edge
    #pragma unroll
    for (int k = 0; k < IPT; ++k)
        if (bk[k] >= 0) pos[k] = atomicAdd(&cnt[bk[k]], 1);
    __syncthreads();

    // phase B: wave 0 scans counts + reserves global ranges (replica `rep`)
    if (tid < NBALL) {
        int h = cnt[tid];
        int v = h;
        #pragma unroll
        for (int off = 1; off < 64; off <<= 1) {
            int u = __shfl_up(v, off);
            if (tid >= off) v += u;
        }
        sbase[tid] = v - h;
        gbase[tid] = atomicAdd(&cursors[(tid << 2) | rep], h);
    }
    __syncthreads();

    // phase C: place records bucket-ordered in LDS
    #pragma unroll
    for (int k = 0; k < IPT; ++k)
        if (bk[k] >= 0) stage[sbase[bk[k]] + pos[k]] = rec[k];
    __syncthreads();

    // phase D: per-wave bucket runs — contiguous LDS reads, coalesced stores
    const int wid = tid >> 6, lane = tid & 63;
    for (int b = wid; b < NBALL; b += NWAVES) {
        const int sb = sbase[b], h = cnt[b], gb = gbase[b];
        unsigned* dstp = records + (size_t)((b << 2) | rep) * capR + gb;
        for (int j = lane; j < h; j += 64)
            __builtin_nontemporal_store(stage[sb + j], dstp + j);
    }
}

// ---------------- pass 2: per-bucket LDS accumulate ----------------
__global__ __launch_bounds__(1024) void k_bins(
    const unsigned* __restrict__ records,
    const int* __restrict__ cursors,
    float* __restrict__ partial,      // [NBUSED*BPB][RANGE]
    int capR)
{
    __shared__ float bins[RANGE];     // 64 KB
    const int b   = blockIdx.x / BPB;
    const int sub = blockIdx.x % BPB;
    const int rep = sub >> 1;
    const int g   = sub & 1;
    const int cnt = cursors[(b << 2) | rep];
    const size_t base = (size_t)((b << 2) | rep) * capR;
    const int lo = (int)((long long)cnt * g       / GSPL);
    const int hi = (int)((long long)cnt * (g + 1) / GSPL);

    for (int i = threadIdx.x; i < RANGE; i += 1024) bins[i] = 0.0f;
    __syncthreads();

    // vectorized 16B record reads
    int i = lo + threadIdx.x * 4;
    for (; i + 4 <= hi; i += 1024 * 4) {
        uv4 r = __builtin_nontemporal_load((const uv4*)(records + base + i));
        #pragma unroll
        for (int k = 0; k < 4; ++k) {
            float v = __half2float(__ushort_as_half((unsigned short)(r[k] >> NB_SHIFT)));
            atomicAdd(&bins[r[k] & (RANGE - 1)], v);
        }
    }
    // tail
    for (int j = lo + ((hi - lo) & ~3) + (int)threadIdx.x; j < hi; j += 1024) {
        unsigned r = __builtin_nontemporal_load(&records[base + j]);
        float v = __half2float(__ushort_as_half((unsigned short)(r >> NB_SHIFT)));
        atomicAdd(&bins[r & (RANGE - 1)], v);
    }
    __syncthreads();

    float* p = partial + (size_t)blockIdx.x * RANGE;
    for (int i2 = threadIdx.x; i2 < RANGE; i2 += 1024)
        __builtin_nontemporal_store(bins[i2], &p[i2]);
}

// ---------------- pass 3: reduce partials + affine ----------------
__global__ __launch_bounds__(256) void k_finalize(
    const float* __restrict__ state,
    const float* __restrict__ partial,
    const float* __restrict__ W,
    const float* __restrict__ bias,
    float* __restrict__ out, int n)
{
    const int i = (blockIdx.x * blockDim.x + threadIdx.x) * 4;
    if (i >= n) return;
    const int b   = i >> NB_SHIFT;
    const int loc = i & (RANGE - 1);
    const float* pb = partial + (size_t)b * BPB * RANGE + loc;
    fv4 s = {0.f, 0.f, 0.f, 0.f};
    #pragma unroll
    for (int g = 0; g < BPB; ++g)
        s += __builtin_nontemporal_load((const fv4*)(pb + (size_t)g * RANGE));
    const float w0 = W[0], w1 = W[1], bb = bias[0];
    fv4 st = *(const fv4*)(state + i);
    fv4 o;
    #pragma unroll
    for (int k = 0; k < 4; ++k) o[k] = fmaf(st[k], w0, fmaf(s[k], w1, bb));
    *(fv4*)(out + i) = o;
}

// ---------------- fallback (ws too small): atomic scatter ----------------
__global__ __launch_bounds__(256) void gnn_zero(float4* __restrict__ ws, int n4) {
    int i = blockIdx.x * blockDim.x + threadIdx.x;
    int stride = gridDim.x * blockDim.x;
    const float4 z = make_float4(0.f, 0.f, 0.f, 0.f);
    for (; i < n4; i += stride) ws[i] = z;
}

__global__ __launch_bounds__(256) void gnn_scatter_dev(const float* __restrict__ state,
                                                       const int* __restrict__ src,
                                                       const int* __restrict__ dst,
                                                       float* __restrict__ nsum,
                                                       int n_edges) {
    const int tid = blockIdx.x * blockDim.x + threadIdx.x;
    const int stride = gridDim.x * blockDim.x;
    const int n4 = n_edges >> 2;
    const int4* __restrict__ src4 = (const int4*)src;
    const int4* __restrict__ dst4 = (const int4*)dst;
    for (int i = tid; i < n4; i += stride) {
        int4 s = src4[i];
        int4 d = dst4[i];
        atomicAdd(&nsum[d.x], state[s.x]);
        atomicAdd(&nsum[d.y], state[s.y]);
        atomicAdd(&nsum[d.z], state[s.z]);
        atomicAdd(&nsum[d.w], state[s.w]);
    }
    for (int i = (n4 << 2) + tid; i < n_edges; i += stride)
        atomicAdd(&nsum[dst[i]], state[src[i]]);
}

__global__ __launch_bounds__(256) void gnn_finalize_flat(const float* __restrict__ state,
                                                         const float* __restrict__ nsum,
                                                         const float* __restrict__ W,
                                                         const float* __restrict__ b,
                                                         float* __restrict__ out, int n) {
    int i = blockIdx.x * blockDim.x + threadIdx.x;
    if (i < n) out[i] = fmaf(state[i], W[0], fmaf(nsum[i], W[1], b[0]));
}

extern "C" void kernel_launch(void* const* d_in, const int* in_sizes, int n_in,
                              void* d_out, int out_size, void* d_ws, size_t ws_size,
                              hipStream_t stream) {
    const float* state = (const float*)d_in[0];
    const int*   esrc  = (const int*)d_in[1];
    const int*   edst  = (const int*)d_in[2];
    const float* W     = (const float*)d_in[3];
    const float* b     = (const float*)d_in[4];
    float* out = (float*)d_out;

    const int n_nodes = in_sizes[0];   // 1,000,000
    const int n_edges = in_sizes[1];   // 32,000,000

    const int nbused = (n_nodes + RANGE - 1) >> NB_SHIFT;              // 62
    const long long lamR = (long long)n_edges * RANGE / n_nodes / NREP; // ~131072
    const int capR = (int)(lamR + lamR / 8 + 1024);                    // ~13% slack

    const size_t shOff   = 0;
    const size_t shBytes = ((size_t)n_nodes * 2 + 255) & ~(size_t)255;
    const size_t recOff  = shBytes;
    const size_t recBytes= ((size_t)NBALL * NREP * capR * 4 + 255) & ~(size_t)255;
    const size_t curOff  = recOff + recBytes;
    const size_t curBytes= (256 * sizeof(int) + 255) & ~(size_t)255;
    const size_t parOff  = curOff + curBytes;
    const size_t parBytes= (size_t)nbused * BPB * RANGE * sizeof(float);
    const size_t need    = parOff + parBytes;

    if (ws_size >= need && (n_nodes & 3) == 0 && (n_edges & 3) == 0) {
        unsigned short* sh = (unsigned short*)((char*)d_ws + shOff);
        unsigned* records  = (unsigned*)((char*)d_ws + recOff);
        int*      cursors  = (int*)((char*)d_ws + curOff);
        float*    partial  = (float*)((char*)d_ws + parOff);

        k_init_cursors<<<1, 256, 0, stream>>>(cursors);
        k_cvt<<<(n_nodes / 4 + 255) / 256, 256, 0, stream>>>(state, sh, n_nodes / 4);

        int tiles = (n_edges + TILE - 1) / TILE;                       // 7813
        k_partition<<<tiles, TPB, 0, stream>>>(sh, esrc, edst,
                                               records, cursors, n_edges, capR);

        k_bins<<<nbused * BPB, 1024, 0, stream>>>(records, cursors, partial, capR);

        int blocks = (n_nodes / 4 + 255) / 256;
        k_finalize<<<blocks, 256, 0, stream>>>(state, partial, W, b, out, n_nodes);
    } else {
        // fallback: device-scope atomic scatter (needs only 4 MB ws)
        float* nsum = (float*)d_ws;
        int n4n = n_nodes >> 2;
        int zb = (n4n + 255) / 256; if (zb > 2048) zb = 2048;
        gnn_zero<<<zb, 256, 0, stream>>>((float4*)nsum, n4n);
        int work = n_edges >> 2;
        int sb = (work + 255) / 256; if (sb > 8192) sb = 8192;
        gnn_scatter_dev<<<sb, 256, 0, stream>>>(state, esrc, edst, nsum, n_edges);
        int fb = (n_nodes + 255) / 256;
        gnn_finalize_flat<<<fb, 256, 0, stream>>>(state, nsum, W, b, out, n_nodes);
    }
}

// Round 6
// 383.629 us; speedup vs baseline: 4.0728x; 1.0077x over previous
//
#include <hip/hip_runtime.h>
#include <hip/hip_fp16.h>

// out[i] = state[i]*W[0] + neighbor_sum[i]*W[1] + b
// neighbor_sum[dst] += state[src] over 32M edges.
//
// Two-level binning, no per-edge global atomics.
//   Pass 0 (k_cvt): state f32 -> f16 table (2MB, L2-resident for gathers).
//   Pass 1 (k_partition): per 4096-edge tile, pack (f16|14-bit local dst),
//     LDS rank by 64 buckets (single LDS atomic/edge), reserve EVEN-sized
//     global ranges on 4-way-replicated cursors (pad slot = zero-record),
//     write records as per-wave bucket runs with 8B paired stores.
//   Pass 2 (k_bins): per (bucket,rep,half) block accumulates into 64KB LDS
//     f32 bins via LDS atomics (uint4 record reads); fv4 zero/writeback.
//   Pass 3 (k_finalize): out = W0*state + W1*sum_8(partial) + b.

#define NB_SHIFT 14
#define RANGE    (1 << NB_SHIFT)       // 16384 nodes per bucket
#define NBALL    64                    // bucket slots (62 used for N=1e6)
#define TPB      512
#define IPT      8
#define TILE     (TPB * IPT)           // 4096 edges per tile
#define NWAVES   (TPB / 64)
#define NREP     4                     // cursor/record-list replicas
#define GSPL     2                     // slices per (bucket,rep) in pass 2
#define BPB      (NREP * GSPL)         // partial slices per bucket = 8

typedef int   iv4 __attribute__((ext_vector_type(4)));
typedef float fv4 __attribute__((ext_vector_type(4)));
typedef unsigned uv4 __attribute__((ext_vector_type(4)));
typedef unsigned uv2 __attribute__((ext_vector_type(2)));

// ---------------- pass 0a: init cursors ----------------
__global__ void k_init_cursors(int* __restrict__ cursors) {
    cursors[threadIdx.x] = 0;          // 256 slots
}

// ---------------- pass 0b: state -> f16 table ----------------
__global__ __launch_bounds__(256) void k_cvt(const float* __restrict__ state,
                                             unsigned short* __restrict__ sh, int n4) {
    int i = blockIdx.x * blockDim.x + threadIdx.x;
    if (i >= n4) return;
    fv4 v = *(const fv4*)(state + i * 4);
    ushort4 h;
    h.x = __half_as_ushort(__float2half_rn(v[0]));
    h.y = __half_as_ushort(__float2half_rn(v[1]));
    h.z = __half_as_ushort(__float2half_rn(v[2]));
    h.w = __half_as_ushort(__float2half_rn(v[3]));
    *(ushort4*)(sh + i * 4) = h;
}

// ---------------- pass 1: partition ----------------
__global__ __launch_bounds__(TPB) void k_partition(
    const unsigned short* __restrict__ sh,   // f16 state bits
    const int* __restrict__ src,
    const int* __restrict__ dst,
    unsigned* __restrict__ records,          // [NBALL*NREP][capR]
    int* __restrict__ cursors,               // [NBALL*NREP]
    int n_edges, int capR)
{
    __shared__ unsigned stage[TILE];
    __shared__ int cnt[NBALL];
    __shared__ int sbase[NBALL];
    __shared__ int gbase[NBALL];

    const int tid = threadIdx.x;
    const int rep = blockIdx.x & (NREP - 1);
    if (tid < NBALL) cnt[tid] = 0;

    const long long e0 = (long long)blockIdx.x * TILE + (long long)tid * IPT;

    unsigned rec[IPT];
    int bk[IPT];
    int pos[IPT];

    if (e0 + IPT <= (long long)n_edges) {
        const long long i4 = e0 >> 2;
        iv4 sA = __builtin_nontemporal_load((const iv4*)src + i4);
        iv4 sB = __builtin_nontemporal_load((const iv4*)src + i4 + 1);
        iv4 dA = __builtin_nontemporal_load((const iv4*)dst + i4);
        iv4 dB = __builtin_nontemporal_load((const iv4*)dst + i4 + 1);
        int s[IPT] = { sA[0], sA[1], sA[2], sA[3], sB[0], sB[1], sB[2], sB[3] };
        int d[IPT] = { dA[0], dA[1], dA[2], dA[3], dB[0], dB[1], dB[2], dB[3] };
        unsigned v[IPT];
        #pragma unroll
        for (int k = 0; k < IPT; ++k) v[k] = sh[s[k]];      // 2B random gather
        #pragma unroll
        for (int k = 0; k < IPT; ++k) {
            bk[k]  = d[k] >> NB_SHIFT;
            rec[k] = (v[k] << NB_SHIFT) | (unsigned)(d[k] & (RANGE - 1));
        }
    } else {
        #pragma unroll
        for (int k = 0; k < IPT; ++k) {
            long long e = e0 + k;
            if (e < n_edges) {
                int d = dst[e];
                unsigned v = sh[src[e]];
                bk[k]  = d >> NB_SHIFT;
                rec[k] = (v << NB_SHIFT) | (unsigned)(d & (RANGE - 1));
            } else {
                bk[k] = -1; rec[k] = 0;
            }
        }
    }
    __syncthreads();   // cnt[] zeroed before first atomic

    // phase A: rank within (tile,bucket) — one LDS atomic per edge
    #pragma unroll
    for (int k = 0; k < IPT; ++k)
        if (bk[k] >= 0) pos[k] = atomicAdd(&cnt[bk[k]], 1);
    __syncthreads();

    // phase B: wave 0 scans counts + reserves EVEN global ranges (replica rep)
    if (tid < NBALL) {
        int h = cnt[tid];
        int v = h;
        #pragma unroll
        for (int off = 1; off < 64; off <<= 1) {
            int u = __shfl_up(v, off);
            if (tid >= off) v += u;
        }
        sbase[tid] = v - h;
        int he = (h + 1) & ~1;                         // even reservation
        gbase[tid] = atomicAdd(&cursors[(tid << 2) | rep], he);
    }
    __syncthreads();

    // phase C: place records bucket-ordered in LDS
    #pragma unroll
    for (int k = 0; k < IPT; ++k)
        if (bk[k] >= 0) stage[sbase[bk[k]] + pos[k]] = rec[k];
    __syncthreads();

    // phase D: per-wave bucket runs — 8B paired nontemporal stores
    const int wid = tid >> 6, lane = tid & 63;
    for (int b = wid; b < NBALL; b += NWAVES) {
        const int sb = sbase[b], h = cnt[b], gb = gbase[b];
        const int hp = (h + 1) >> 1;                   // pairs (incl. pad)
        unsigned* dstp = records + (size_t)((b << 2) | rep) * capR + gb;
        for (int j = lane; j < hp; j += 64) {
            uv2 r;
            r[0] = stage[sb + 2 * j];
            r[1] = (2 * j + 1 < h) ? stage[sb + 2 * j + 1] : 0u;  // pad: +0.0 to bin 0
            __builtin_nontemporal_store(r, (uv2*)(dstp + 2 * j));
        }
    }
}

// ---------------- pass 2: per-bucket LDS accumulate ----------------
__global__ __launch_bounds__(1024) void k_bins(
    const unsigned* __restrict__ records,
    const int* __restrict__ cursors,
    float* __restrict__ partial,      // [NBUSED*BPB][RANGE]
    int capR)
{
    __shared__ float bins[RANGE];     // 64 KB
    const int b   = blockIdx.x / BPB;
    const int sub = blockIdx.x % BPB;
    const int rep = sub >> 1;
    const int g   = sub & 1;
    const int cnt = cursors[(b << 2) | rep];
    const size_t base = (size_t)((b << 2) | rep) * capR;
    const int lo = (int)((long long)cnt * g       / GSPL);
    const int hi = (int)((long long)cnt * (g + 1) / GSPL);
    const int tid = threadIdx.x;

    fv4* bins4 = (fv4*)bins;
    for (int i = tid; i < RANGE / 4; i += 1024) bins4[i] = (fv4){0.f, 0.f, 0.f, 0.f};
    __syncthreads();

    // head: align to 4 records
    int A = (lo + 3) & ~3; if (A > hi) A = hi;
    if (tid < A - lo) {
        unsigned r = records[base + lo + tid];
        float v = __half2float(__ushort_as_half((unsigned short)(r >> NB_SHIFT)));
        atomicAdd(&bins[r & (RANGE - 1)], v);
    }
    // body: uint4 reads
    for (int i = A + tid * 4; i + 4 <= hi; i += 1024 * 4) {
        uv4 r = __builtin_nontemporal_load((const uv4*)(records + base + i));
        #pragma unroll
        for (int k = 0; k < 4; ++k) {
            float v = __half2float(__ushort_as_half((unsigned short)(r[k] >> NB_SHIFT)));
            atomicAdd(&bins[r[k] & (RANGE - 1)], v);
        }
    }
    // tail
    {
        int start = A + ((hi - A) & ~3);
        if (tid < hi - start) {
            unsigned r = records[base + start + tid];
            float v = __half2float(__ushort_as_half((unsigned short)(r >> NB_SHIFT)));
            atomicAdd(&bins[r & (RANGE - 1)], v);
        }
    }
    __syncthreads();

    float* p = partial + (size_t)blockIdx.x * RANGE;
    for (int i = tid; i < RANGE / 4; i += 1024)
        __builtin_nontemporal_store(bins4[i], (fv4*)p + i);
}

// ---------------- pass 3: reduce partials + affine ----------------
__global__ __launch_bounds__(256) void k_finalize(
    const float* __restrict__ state,
    const float* __restrict__ partial,
    const float* __restrict__ W,
    const float* __restrict__ bias,
    float* __restrict__ out, int n)
{
    const int i = (blockIdx.x * blockDim.x + threadIdx.x) * 4;
    if (i >= n) return;
    const int b   = i >> NB_SHIFT;
    const int loc = i & (RANGE - 1);
    const float* pb = partial + (size_t)b * BPB * RANGE + loc;
    fv4 s = {0.f, 0.f, 0.f, 0.f};
    #pragma unroll
    for (int g = 0; g < BPB; ++g)
        s += __builtin_nontemporal_load((const fv4*)(pb + (size_t)g * RANGE));
    const float w0 = W[0], w1 = W[1], bb = bias[0];
    fv4 st = *(const fv4*)(state + i);
    fv4 o;
    #pragma unroll
    for (int k = 0; k < 4; ++k) o[k] = fmaf(st[k], w0, fmaf(s[k], w1, bb));
    *(fv4*)(out + i) = o;
}

// ---------------- fallback (ws too small): atomic scatter ----------------
__global__ __launch_bounds__(256) void gnn_zero(float4* __restrict__ ws, int n4) {
    int i = blockIdx.x * blockDim.x + threadIdx.x;
    int stride = gridDim.x * blockDim.x;
    const float4 z = make_float4(0.f, 0.f, 0.f, 0.f);
    for (; i < n4; i += stride) ws[i] = z;
}

__global__ __launch_bounds__(256) void gnn_scatter_dev(const float* __restrict__ state,
                                                       const int* __restrict__ src,
                                                       const int* __restrict__ dst,
                                                       float* __restrict__ nsum,
                                                       int n_edges) {
    const int tid = blockIdx.x * blockDim.x + threadIdx.x;
    const int stride = gridDim.x * blockDim.x;
    const int n4 = n_edges >> 2;
    const int4* __restrict__ src4 = (const int4*)src;
    const int4* __restrict__ dst4 = (const int4*)dst;
    for (int i = tid; i < n4; i += stride) {
        int4 s = src4[i];
        int4 d = dst4[i];
        atomicAdd(&nsum[d.x], state[s.x]);
        atomicAdd(&nsum[d.y], state[s.y]);
        atomicAdd(&nsum[d.z], state[s.z]);
        atomicAdd(&nsum[d.w], state[s.w]);
    }
    for (int i = (n4 << 2) + tid; i < n_edges; i += stride)
        atomicAdd(&nsum[dst[i]], state[src[i]]);
}

__global__ __launch_bounds__(256) void gnn_finalize_flat(const float* __restrict__ state,
                                                         const float* __restrict__ nsum,
                                                         const float* __restrict__ W,
                                                         const float* __restrict__ b,
                                                         float* __restrict__ out, int n) {
    int i = blockIdx.x * blockDim.x + threadIdx.x;
    if (i < n) out[i] = fmaf(state[i], W[0], fmaf(nsum[i], W[1], b[0]));
}

extern "C" void kernel_launch(void* const* d_in, const int* in_sizes, int n_in,
                              void* d_out, int out_size, void* d_ws, size_t ws_size,
                              hipStream_t stream) {
    const float* state = (const float*)d_in[0];
    const int*   esrc  = (const int*)d_in[1];
    const int*   edst  = (const int*)d_in[2];
    const float* W     = (const float*)d_in[3];
    const float* b     = (const float*)d_in[4];
    float* out = (float*)d_out;

    const int n_nodes = in_sizes[0];   // 1,000,000
    const int n_edges = in_sizes[1];   // 32,000,000

    const int nbused = (n_nodes + RANGE - 1) >> NB_SHIFT;              // 62
    const long long lamR = (long long)n_edges * RANGE / n_nodes / NREP; // ~131072
    const int capR = (int)(lamR + lamR / 8 + 4096);                    // slack + even-pad

    const size_t shOff   = 0;
    const size_t shBytes = ((size_t)n_nodes * 2 + 255) & ~(size_t)255;
    const size_t recOff  = shBytes;
    const size_t recBytes= ((size_t)NBALL * NREP * capR * 4 + 255) & ~(size_t)255;
    const size_t curOff  = recOff + recBytes;
    const size_t curBytes= (256 * sizeof(int) + 255) & ~(size_t)255;
    const size_t parOff  = curOff + curBytes;
    const size_t parBytes= (size_t)nbused * BPB * RANGE * sizeof(float);
    const size_t need    = parOff + parBytes;

    if (ws_size >= need && (n_nodes & 3) == 0 && (n_edges & 3) == 0) {
        unsigned short* sh = (unsigned short*)((char*)d_ws + shOff);
        unsigned* records  = (unsigned*)((char*)d_ws + recOff);
        int*      cursors  = (int*)((char*)d_ws + curOff);
        float*    partial  = (float*)((char*)d_ws + parOff);

        k_init_cursors<<<1, 256, 0, stream>>>(cursors);
        k_cvt<<<(n_nodes / 4 + 255) / 256, 256, 0, stream>>>(state, sh, n_nodes / 4);

        int tiles = (n_edges + TILE - 1) / TILE;                       // 7813
        k_partition<<<tiles, TPB, 0, stream>>>(sh, esrc, edst,
                                               records, cursors, n_edges, capR);

        k_bins<<<nbused * BPB, 1024, 0, stream>>>(records, cursors, partial, capR);

        int blocks = (n_nodes / 4 + 255) / 256;
        k_finalize<<<blocks, 256, 0, stream>>>(state, partial, W, b, out, n_nodes);
    } else {
        // fallback: device-scope atomic scatter (needs only 4 MB ws)
        float* nsum = (float*)d_ws;
        int n4n = n_nodes >> 2;
        int zb = (n4n + 255) / 256; if (zb > 2048) zb = 2048;
        gnn_zero<<<zb, 256, 0, stream>>>((float4*)nsum, n4n);
        int work = n_edges >> 2;
        int sb = (work + 255) / 256; if (sb > 8192) sb = 8192;
        gnn_scatter_dev<<<sb, 256, 0, stream>>>(state, esrc, edst, nsum, n_edges);
        int fb = (n_nodes + 255) / 256;
        gnn_finalize_flat<<<fb, 256, 0, stream>>>(state, nsum, W, b, out, n_nodes);
    }
}